// Round 3
// baseline (653.387 us; speedup 1.0000x reference)
//
#include <hip/hip_runtime.h>
#include <hip/hip_bf16.h>
#include <stdint.h>

// Problem constants
#define N_B   512
#define D_K   512
#define C_N   50000
#define BM    128
#define BN    128
#define BK    32
#define NCB   391          // ceil(C_N/BN)

#define S_SCALE 30.0f
#define COS_Mc  0.87758256189037276f
#define SIN_Mc  0.47942553860420301f
#define TH_Cc  (-0.87758256189037276f)
#define MM_Cc   0.23971276930210156f
#define SHIFT   30.0f      // outputs <= 30 => exp(o-30) in [exp(-67),1], never overflows

typedef __attribute__((ext_vector_type(8))) __bf16 bf16x8;
typedef __attribute__((ext_vector_type(4))) float  f32x4;

__device__ __forceinline__ unsigned short f2bf(float f) {
    union { float f; unsigned u; } v; v.f = f;
    unsigned r = v.u + 0x7FFFu + ((v.u >> 16) & 1u);   // RNE
    return (unsigned short)(r >> 16);
}

__device__ __forceinline__ unsigned pk2(float a, float b) {
    __hip_bfloat162 h = __float22bfloat162_rn(float2{a, b});
    union { __hip_bfloat162 h; unsigned u; } c; c.h = h;
    return c.u;
}

__device__ __forceinline__ void gl2lds16(const void* g, void* l) {
    __builtin_amdgcn_global_load_lds(
        (__attribute__((address_space(1))) unsigned int*)(g),
        (__attribute__((address_space(3))) unsigned int*)(l),
        16, 0, 0);
}

// x prep: one wave per row, exact fp32 inverse L2 norm + bf16 convert.
__global__ __launch_bounds__(256) void prep_x_kernel(
        const float* __restrict__ src, unsigned short* __restrict__ dstb,
        float* __restrict__ inv)
{
    int wave = threadIdx.x >> 6, lane = threadIdx.x & 63;
    int row = blockIdx.x * 4 + wave;
    const float4* s4 = (const float4*)(src + (size_t)row * D_K) + lane * 2;
    float4 a = s4[0], b = s4[1];
    float ss = a.x*a.x + a.y*a.y + a.z*a.z + a.w*a.w
             + b.x*b.x + b.y*b.y + b.z*b.z + b.w*b.w;
    #pragma unroll
    for (int off = 32; off >= 1; off >>= 1) ss += __shfl_xor(ss, off, 64);
    if (lane == 0) inv[row] = 1.0f / fmaxf(sqrtf(ss), 1e-12f);
    uint4 o;
    o.x = (unsigned)f2bf(a.x) | ((unsigned)f2bf(a.y) << 16);
    o.y = (unsigned)f2bf(a.z) | ((unsigned)f2bf(a.w) << 16);
    o.z = (unsigned)f2bf(b.x) | ((unsigned)f2bf(b.y) << 16);
    o.w = (unsigned)f2bf(b.z) | ((unsigned)f2bf(b.w) << 16);
    *(uint4*)(dstb + (size_t)row * D_K + lane * 8) = o;
}

// 128x128 GEMM tile. A = bf16 xb via DMA; B = fp32 W via DMA (read ONCE from
// HBM, no prep pass), converted to bf16 at fragment-read; invw accumulated
// from fp32 B fragments. Double-buffered LDS + raw-asm barriers:
//   barrier1 = s_waitcnt vmcnt(6); s_barrier   (only cur-iter DMA drained)
//   barrier2 = s_waitcnt lgkmcnt(0); s_barrier (buffer release, no vm drain)
// so next-iter DMA stays in flight across the whole compute phase.
__global__ __launch_bounds__(256, 3) void gemm3_kernel(
        const unsigned short* __restrict__ xb, const float* __restrict__ w,
        const float* __restrict__ invx, const int* __restrict__ labels,
        float* __restrict__ out, float* __restrict__ s_part)
{
    const int rb = blockIdx.x, cb = blockIdx.y;
    const int m0 = rb * BM, c0 = cb * BN;
    const int tid = threadIdx.x;
    const int lane = tid & 63, wave = tid >> 6;
    const int wm = wave >> 1, wn = wave & 1;
    const int l15 = lane & 15, q = lane >> 4;

    __shared__ __align__(16) unsigned short As[2][BM * BK];  // 2 x 8 KB
    __shared__ __align__(16) float          Bs[2][BN * BK];  // 2 x 16 KB
    __shared__ float s_invx[BM];
    __shared__ int   s_lab[BM];

    if (tid < BM) { s_invx[tid] = invx[m0 + tid]; s_lab[tid] = labels[m0 + tid]; }

    // --- staging addresses ---
    // A: thread stages rows srow and srow+64, 16B chunk pcA, swizzled source.
    const int srow = tid >> 2, pcA = tid & 3;
    const int kcA = pcA ^ ((srow >> 1) & 3);   // same for srow and srow+64
    const unsigned short* gA0 = xb + (size_t)(m0 + srow) * D_K + kcA * 8;
    const unsigned short* gA1 = gA0 + (size_t)64 * D_K;
    // B: thread stages 4 cols (colB + 32s), 16B chunk pcB, swizzled source.
    const int colB = tid >> 3, pcB = tid & 7;
    const int kcB = pcB ^ (colB & 7);          // (colB+32s)&7 == colB&7
    const float* gB[4];
    #pragma unroll
    for (int s = 0; s < 4; s++) {
        int scol = c0 + colB + 32 * s;
        if (scol >= C_N) scol = C_N - 1;       // clamp OOB pad cols (guarded later)
        gB[s] = w + (size_t)scol * D_K + kcB * 4;
    }
    // fragment read offsets
    int aoff[4], bcol[4];
    #pragma unroll
    for (int i = 0; i < 4; i++) {
        int Ra = wm * 64 + i * 16 + l15;
        aoff[i] = Ra * BK + (q ^ ((Ra >> 1) & 3)) * 8;
        bcol[i] = wn * 64 + i * 16 + l15;
    }

    __syncthreads();   // drains everything; clean vmcnt slate

    f32x4 zero4 = {0.f, 0.f, 0.f, 0.f};
    f32x4 acc[4][4];
    #pragma unroll
    for (int i = 0; i < 4; i++)
        #pragma unroll
        for (int j = 0; j < 4; j++) acc[i][j] = zero4;
    float ssw[4] = {0.f, 0.f, 0.f, 0.f};

    // prologue: stage ks=0 into buf 0
    gl2lds16(gA0, &As[0][tid * 8]);
    gl2lds16(gA1, &As[0][2048 + tid * 8]);
    #pragma unroll
    for (int s = 0; s < 4; s++) gl2lds16(gB[s], &Bs[0][s * 1024 + tid * 4]);

    #pragma unroll
    for (int ks = 0; ks < 16; ks++) {
        const int cur = ks & 1, nxt = cur ^ 1;
        if (ks + 1 < 16) {
            const int k0 = (ks + 1) * BK;
            gl2lds16(gA0 + k0, &As[nxt][tid * 8]);
            gl2lds16(gA1 + k0, &As[nxt][2048 + tid * 8]);
            #pragma unroll
            for (int s = 0; s < 4; s++)
                gl2lds16(gB[s] + k0, &Bs[nxt][s * 1024 + tid * 4]);
            asm volatile("s_waitcnt vmcnt(6)\n\ts_barrier" ::: "memory");
        } else {
            asm volatile("s_waitcnt vmcnt(0)\n\ts_barrier" ::: "memory");
        }

        bf16x8 af[4];
        #pragma unroll
        for (int mi = 0; mi < 4; mi++)
            af[mi] = *(const bf16x8*)(&As[cur][aoff[mi]]);

        bf16x8 bfr[4];
        #pragma unroll
        for (int ni = 0; ni < 4; ni++) {
            const float* bp = &Bs[cur][bcol[ni] * BK];
            const int x7 = bcol[ni] & 7;
            float4 f0 = *(const float4*)(bp + ((2 * q) ^ x7) * 4);
            float4 f1 = *(const float4*)(bp + ((2 * q + 1) ^ x7) * 4);
            ssw[ni] += f0.x*f0.x + f0.y*f0.y + f0.z*f0.z + f0.w*f0.w
                     + f1.x*f1.x + f1.y*f1.y + f1.z*f1.z + f1.w*f1.w;
            union { bf16x8 v; unsigned u[4]; } cvt;
            cvt.u[0] = pk2(f0.x, f0.y); cvt.u[1] = pk2(f0.z, f0.w);
            cvt.u[2] = pk2(f1.x, f1.y); cvt.u[3] = pk2(f1.z, f1.w);
            bfr[ni] = cvt.v;
        }

        #pragma unroll
        for (int mi = 0; mi < 4; mi++)
            #pragma unroll
            for (int ni = 0; ni < 4; ni++)
                acc[mi][ni] = __builtin_amdgcn_mfma_f32_16x16x32_bf16(
                                  af[mi], bfr[ni], acc[mi][ni], 0, 0, 0);

        if (ks + 1 < 16)
            asm volatile("s_waitcnt lgkmcnt(0)\n\ts_barrier" ::: "memory");
    }

    // invw per owned column: ssw covers this lane's q-chunk; sum over q-quads.
    float invw_[4];
    #pragma unroll
    for (int ni = 0; ni < 4; ni++) {
        float ss = ssw[ni];
        ss += __shfl_xor(ss, 16, 64);
        ss += __shfl_xor(ss, 32, 64);
        invw_[ni] = 1.0f / fmaxf(sqrtf(ss), 1e-12f);
    }

    // Epilogue. C/D layout: col = lane&15, row = (lane>>4)*4 + reg
    #pragma unroll
    for (int mi = 0; mi < 4; mi++) {
        #pragma unroll
        for (int r = 0; r < 4; r++) {
            int lrow = wm * 64 + mi * 16 + q * 4 + r;
            int grow = m0 + lrow;
            float ivx = s_invx[lrow];
            int lab = s_lab[lrow];
            float es = 0.f;
            #pragma unroll
            for (int ni = 0; ni < 4; ni++) {
                int gcol = c0 + wn * 64 + ni * 16 + l15;
                float cosv = acc[mi][ni][r] * ivx * invw_[ni];
                float o = S_SCALE * cosv;
                if (gcol == lab) {
                    float s2 = fminf(fmaxf(1.0f + 1e-7f - cosv * cosv, 0.f), 1.f);
                    float phi = cosv * COS_Mc - sqrtf(s2) * SIN_Mc;
                    if (!(cosv > TH_Cc)) phi = cosv - MM_Cc;
                    o = S_SCALE * phi;
                }
                if (gcol < C_N) {
                    out[(size_t)grow * C_N + gcol] = o;
                    es += __expf(o - SHIFT);
                }
            }
            es += __shfl_xor(es, 1, 64);
            es += __shfl_xor(es, 2, 64);
            es += __shfl_xor(es, 4, 64);
            es += __shfl_xor(es, 8, 64);
            // col-halves (wn) write disjoint slabs; merged in rowreduce.
            if (l15 == 0) s_part[((size_t)wn * NCB + cb) * N_B + grow] = es;
        }
    }
}

// Merge 2*NCB partial exp-sums per row -> logZ -> per-row loss term.
__global__ void rowreduce_kernel(
        const float* __restrict__ s_part, const float* __restrict__ out,
        const int* __restrict__ labels, float* __restrict__ lossp)
{
    int b = blockIdx.x;                    // 0..7
    int r = b * 64 + (threadIdx.x & 63);
    int c = threadIdx.x >> 6;              // 0..7
    float s = 0.f;
    for (int j = c; j < 2 * NCB; j += 8) s += s_part[(size_t)j * N_B + r];
    __shared__ float pt[8][64];
    pt[c][threadIdx.x & 63] = s;
    __syncthreads();
    if (threadIdx.x < 64) {
        int row = b * 64 + threadIdx.x;
        float t = 0.f;
        #pragma unroll
        for (int cc = 0; cc < 8; cc++) t += pt[cc][threadIdx.x];
        float logZ = SHIFT + logf(t);
        lossp[row] = logZ - out[(size_t)row * C_N + labels[row]];
    }
}

__global__ void loss_kernel(const float* __restrict__ lossp, float* __restrict__ loss_out) {
    int t = threadIdx.x;   // blockDim = 256
    float v = lossp[t] + lossp[t + 256];
    #pragma unroll
    for (int off = 32; off >= 1; off >>= 1) v += __shfl_xor(v, off, 64);
    __shared__ float part[4];
    if ((t & 63) == 0) part[t >> 6] = v;
    __syncthreads();
    if (t == 0) loss_out[0] = (part[0] + part[1] + part[2] + part[3]) * (1.0f / 512.0f);
}

extern "C" void kernel_launch(void* const* d_in, const int* in_sizes, int n_in,
                              void* d_out, int out_size, void* d_ws, size_t ws_size,
                              hipStream_t stream)
{
    const float* x      = (const float*)d_in[0];
    const int*   labels = (const int*)d_in[1];
    const float* w      = (const float*)d_in[2];
    float* out = (float*)d_out;
    float* loss_out = out + (size_t)N_B * C_N;

    char* ws = (char*)d_ws;
    size_t off = 0;
    unsigned short* xb = (unsigned short*)(ws + off); off += (size_t)N_B * D_K * 2;   // 512 KB
    float* invx   = (float*)(ws + off); off += (size_t)N_B * 4;
    float* s_part = (float*)(ws + off); off += (size_t)2 * NCB * N_B * 4;             // 1.6 MB
    float* lossp  = (float*)(ws + off); off += (size_t)N_B * 4;

    prep_x_kernel<<<N_B / 4, 256, 0, stream>>>(x, xb, invx);
    gemm3_kernel<<<dim3(4, NCB), 256, 0, stream>>>(xb, w, invx, labels, out, s_part);
    rowreduce_kernel<<<8, 512, 0, stream>>>(s_part, out, labels, lossp);
    loss_kernel<<<1, 256, 0, stream>>>(lossp, loss_out);
}

// Round 4
// 283.975 us; speedup vs baseline: 2.3009x; 2.3009x over previous
//
#include <hip/hip_runtime.h>
#include <stdint.h>

// Problem constants
#define N_B   512
#define D_K   512
#define C_N   50000
#define C_PAD 50048        // 391*128
#define BM    128
#define BN    128
#define BK    64
#define NCB   391          // C_PAD / BN

#define S_SCALE 30.0f
#define COS_Mc  0.87758256189037276f
#define SIN_Mc  0.47942553860420301f
#define TH_Cc  (-0.87758256189037276f)
#define MM_Cc   0.23971276930210156f
#define SHIFT   30.0f      // outputs <= 30 => exp(o-30) in [exp(-67),1]

typedef __attribute__((ext_vector_type(8))) __bf16 bf16x8;
typedef __attribute__((ext_vector_type(4))) float  f32x4;

__device__ __forceinline__ unsigned short f2bf(float f) {
    union { float f; unsigned u; } v; v.f = f;
    unsigned r = v.u + 0x7FFFu + ((v.u >> 16) & 1u);   // RNE
    return (unsigned short)(r >> 16);
}

__device__ __forceinline__ void gl2lds16(const void* g, void* l) {
    __builtin_amdgcn_global_load_lds(
        (__attribute__((address_space(1))) unsigned int*)(g),
        (__attribute__((address_space(3))) unsigned int*)(l),
        16, 0, 0);
}

// One wave per row: exact fp32 inverse L2 norm + bf16 conversion.
// Rows in [nvalid, ntotal) are zero padding (inv=0, bf16 row = 0).
// Block 0 / thread 0 also zeroes loss_out (used by rowreduce's atomicAdd).
__global__ __launch_bounds__(256) void prep_kernel(
        const float* __restrict__ src, unsigned short* __restrict__ dstb,
        float* __restrict__ inv, int nvalid, int ntotal,
        float* __restrict__ zero_me)
{
    if (zero_me && blockIdx.x == 0 && threadIdx.x == 0) *zero_me = 0.f;
    int wave = threadIdx.x >> 6, lane = threadIdx.x & 63;
    int row = blockIdx.x * 4 + wave;
    if (row >= ntotal) return;
    unsigned short* dst = dstb + (size_t)row * D_K + lane * 8;
    if (row < nvalid) {
        const float4* s4 = (const float4*)(src + (size_t)row * D_K) + lane * 2;
        float4 a = s4[0], b = s4[1];
        float ss = a.x*a.x + a.y*a.y + a.z*a.z + a.w*a.w
                 + b.x*b.x + b.y*b.y + b.z*b.z + b.w*b.w;
        #pragma unroll
        for (int off = 32; off >= 1; off >>= 1) ss += __shfl_xor(ss, off, 64);
        if (lane == 0) inv[row] = 1.0f / fmaxf(sqrtf(ss), 1e-12f);
        uint4 o;
        o.x = (unsigned)f2bf(a.x) | ((unsigned)f2bf(a.y) << 16);
        o.y = (unsigned)f2bf(a.z) | ((unsigned)f2bf(a.w) << 16);
        o.z = (unsigned)f2bf(b.x) | ((unsigned)f2bf(b.y) << 16);
        o.w = (unsigned)f2bf(b.z) | ((unsigned)f2bf(b.w) << 16);
        *(uint4*)dst = o;
    } else {
        *(uint4*)dst = make_uint4(0u, 0u, 0u, 0u);
        if (lane == 0) inv[row] = 0.0f;
    }
}

// 128x128 tile, BK=64 (8 barrier-pairs), bf16 MFMA, global_load_lds staging.
// LDS layout: row-major, 8 chunks of 16B per row, physical chunk =
// logical_chunk ^ (row & 7)  (swizzle applied on the GLOBAL SOURCE address so
// the LDS destination stays identity lane order, as the DMA requires).
// Epilogue: cosine scale, arc-margin at label col, store S*val, fixed-shift
// exp-sum partial per (wave-col-half, col-block).
__global__ __launch_bounds__(256) void gemm4_kernel(
        const unsigned short* __restrict__ xb, const unsigned short* __restrict__ wb,
        const float* __restrict__ invx, const float* __restrict__ invw,
        const int* __restrict__ labels, float* __restrict__ out,
        float* __restrict__ s_part)
{
    const int cb = blockIdx.x, rb = blockIdx.y;   // cb FAST (proven L3-friendly)
    const int m0 = rb * BM, c0 = cb * BN;
    const int tid = threadIdx.x;
    const int lane = tid & 63, wave = tid >> 6;
    const int wm = wave >> 1, wn = wave & 1;
    const int l15 = lane & 15, q = lane >> 4;

    __shared__ __align__(16) unsigned short As[BM * BK];   // 16 KB
    __shared__ __align__(16) unsigned short Bs[BN * BK];   // 16 KB
    __shared__ float s_invx[BM];
    __shared__ float s_invw[BN];
    __shared__ int   s_lab[BM];

    if (tid < BM) {
        s_invx[tid] = invx[m0 + tid];
        s_lab[tid]  = labels[m0 + tid];
        s_invw[tid] = invw[c0 + tid];
    }

    // DMA plan: flat chunk id f = j*256 + tid, j=0..3; row = f>>3, physical
    // chunk pc = f&7, logical (source) chunk lc = pc ^ (row&7).
    // LDS dest bytes = f*16 -> wave-uniform base + lane*16. Source: 8
    // consecutive lanes cover one row's 8 chunks (permuted) = one 128B line.
    const unsigned short* gA[4]; const unsigned short* gB[4];
    unsigned short* lA[4]; unsigned short* lB[4];
    #pragma unroll
    for (int j = 0; j < 4; j++) {
        int f = j * 256 + tid;
        int row = f >> 3, lc = (f & 7) ^ (row & 7);
        gA[j] = xb + (size_t)(m0 + row) * D_K + lc * 8;
        gB[j] = wb + (size_t)(c0 + row) * D_K + lc * 8;
        lA[j] = As + f * 8;
        lB[j] = Bs + f * 8;
    }

    // Fragment read bases: row R at ushort R*64, chunk t*4+q swizzled by R&7.
    int abase[4], axor[4], bbase[4], bxor[4];
    #pragma unroll
    for (int i = 0; i < 4; i++) {
        int Ra = wm * 64 + i * 16 + l15;
        abase[i] = Ra * BK; axor[i] = Ra & 7;
        int Rb = wn * 64 + i * 16 + l15;
        bbase[i] = Rb * BK; bxor[i] = Rb & 7;
    }

    f32x4 zero4 = {0.f, 0.f, 0.f, 0.f};
    f32x4 acc[4][4];
    #pragma unroll
    for (int i = 0; i < 4; i++)
        #pragma unroll
        for (int j = 0; j < 4; j++) acc[i][j] = zero4;

    for (int ks = 0; ks < 8; ks++) {
        const int k0 = ks * BK;
        #pragma unroll
        for (int j = 0; j < 4; j++) gl2lds16(gA[j] + k0, lA[j]);
        #pragma unroll
        for (int j = 0; j < 4; j++) gl2lds16(gB[j] + k0, lB[j]);
        __syncthreads();

        #pragma unroll
        for (int t = 0; t < 2; t++) {
            bf16x8 af[4], bfr[4];
            #pragma unroll
            for (int i = 0; i < 4; i++)
                af[i] = *(const bf16x8*)(As + abase[i] + (((t*4 + q) ^ axor[i]) << 3));
            #pragma unroll
            for (int i = 0; i < 4; i++)
                bfr[i] = *(const bf16x8*)(Bs + bbase[i] + (((t*4 + q) ^ bxor[i]) << 3));
            #pragma unroll
            for (int mi = 0; mi < 4; mi++)
                #pragma unroll
                for (int ni = 0; ni < 4; ni++)
                    acc[mi][ni] = __builtin_amdgcn_mfma_f32_16x16x32_bf16(
                                      af[mi], bfr[ni], acc[mi][ni], 0, 0, 0);
        }
        __syncthreads();
    }

    // Epilogue. C/D layout: col = lane&15, row = (lane>>4)*4 + reg
    #pragma unroll
    for (int mi = 0; mi < 4; mi++) {
        #pragma unroll
        for (int r = 0; r < 4; r++) {
            int lrow = wm * 64 + mi * 16 + q * 4 + r;
            int grow = m0 + lrow;
            float ivx = s_invx[lrow];
            int lab = s_lab[lrow];
            float es = 0.f;
            #pragma unroll
            for (int ni = 0; ni < 4; ni++) {
                int lcol = wn * 64 + ni * 16 + l15;
                int gcol = c0 + lcol;
                float cosv = acc[mi][ni][r] * ivx * s_invw[lcol];
                float o = S_SCALE * cosv;
                if (gcol == lab) {
                    float s2 = fminf(fmaxf(1.0f + 1e-7f - cosv * cosv, 0.f), 1.f);
                    float phi = cosv * COS_Mc - sqrtf(s2) * SIN_Mc;
                    if (!(cosv > TH_Cc)) phi = cosv - MM_Cc;
                    o = S_SCALE * phi;
                }
                if (gcol < C_N) {
                    out[(size_t)grow * C_N + gcol] = o;
                    es += __expf(o - SHIFT);
                }
            }
            es += __shfl_xor(es, 1, 64);
            es += __shfl_xor(es, 2, 64);
            es += __shfl_xor(es, 4, 64);
            es += __shfl_xor(es, 8, 64);
            if (l15 == 0) s_part[((size_t)wn * NCB + cb) * N_B + grow] = es;
        }
    }
}

// Merge 2*NCB partial exp-sums per row -> logZ -> loss contribution (atomic).
__global__ void rowreduce_kernel(
        const float* __restrict__ s_part, const float* __restrict__ out,
        const int* __restrict__ labels, float* __restrict__ loss_out)
{
    int b = blockIdx.x;                    // 0..7
    int r = b * 64 + (threadIdx.x & 63);
    int c = threadIdx.x >> 6;              // 0..7
    float s = 0.f;
    for (int j = c; j < 2 * NCB; j += 8) s += s_part[(size_t)j * N_B + r];
    __shared__ float pt[8][64];
    pt[c][threadIdx.x & 63] = s;
    __syncthreads();
    if (threadIdx.x < 64) {
        int row = b * 64 + threadIdx.x;
        float t = 0.f;
        #pragma unroll
        for (int cc = 0; cc < 8; cc++) t += pt[cc][threadIdx.x];
        float logZ = SHIFT + logf(t);
        float contrib = (logZ - out[(size_t)row * C_N + labels[row]]) * (1.0f / 512.0f);
        #pragma unroll
        for (int off = 32; off >= 1; off >>= 1) contrib += __shfl_xor(contrib, off, 64);
        if (threadIdx.x == 0) atomicAdd(loss_out, contrib);
    }
}

extern "C" void kernel_launch(void* const* d_in, const int* in_sizes, int n_in,
                              void* d_out, int out_size, void* d_ws, size_t ws_size,
                              hipStream_t stream)
{
    const float* x      = (const float*)d_in[0];
    const int*   labels = (const int*)d_in[1];
    const float* w      = (const float*)d_in[2];
    float* out = (float*)d_out;
    float* loss_out = out + (size_t)N_B * C_N;

    char* ws = (char*)d_ws;
    size_t off = 0;
    unsigned short* xb = (unsigned short*)(ws + off); off += (size_t)N_B * D_K * 2;     // 512 KB
    unsigned short* wb = (unsigned short*)(ws + off); off += (size_t)C_PAD * D_K * 2;   // 51.2 MB
    float* invx   = (float*)(ws + off); off += (size_t)N_B * 4;
    float* invw   = (float*)(ws + off); off += (size_t)C_PAD * 4;
    float* s_part = (float*)(ws + off); off += (size_t)2 * NCB * N_B * 4;               // 1.6 MB

    prep_kernel<<<N_B / 4, 256, 0, stream>>>(x, xb, invx, N_B, N_B, loss_out);
    prep_kernel<<<C_PAD / 4, 256, 0, stream>>>(w, wb, invw, C_N, C_PAD, (float*)nullptr);
    gemm4_kernel<<<dim3(NCB, N_B / BM), 256, 0, stream>>>(xb, wb, invx, invw, labels,
                                                          out, s_part);
    rowreduce_kernel<<<8, 512, 0, stream>>>(s_part, out, labels, loss_out);
}